// Round 4
// baseline (439.262 us; speedup 1.0000x reference)
//
#include <hip/hip_runtime.h>
#include <hip/hip_bf16.h>
#include <hip/hip_fp16.h>

#define NN 100000      // nodes
#define NE 1000000     // edges
#define NPART 391      // ceil(NN/256)
#define NB2 977        // ceil((NE/4)/256)  edge-parallel grid, 4 edges/thread

// ---------------- workspace layout (4-byte units) ----------------
// Edge-parallel design: NO rank, NO scan, NO CSR scatter.
#define OFF_PFEAT    0              // float4[NN]  {f0,f1,f2,el1}
#define OFF_ER1      400000         // f32[NN]
#define OFF_A0       500000         // f32[NN*4] stride-4 (SoA accum: p*f0)
#define OFF_A1       900000         // f32[NN*4] (p*f1)
#define OFF_A2       1300000        // f32[NN*4] (p*f2)
#define OFF_A3       1700000        // f32[NN*4] (p)
#define OFF_ER2      2100000        // f32[NN]
#define OFF_DEN2     2200000        // f32[NN*4] stride-4 (layer-2 softmax denom)
#define OFF_Z2H      2600000        // half[32*NN] (64B rows; [30]=el2, [31]=0)
#define OFF_PARTS    4200000        // f32[NB2*32]

#define PK2(a,b) __builtin_bit_cast(float, __floats2half2_rn((a),(b)))

// per-block cl/cr compute (redundant, cheap) + pack pfeat/er1 + zero layer-1 accums
__global__ void k0_prep(const float* __restrict__ feat, const float* __restrict__ W1,
                        const float* __restrict__ al1, const float* __restrict__ ar1,
                        float4* __restrict__ pfeat, float* __restrict__ er1,
                        float4* __restrict__ a0, float4* __restrict__ a1,
                        float4* __restrict__ a2, float4* __restrict__ a3) {
    __shared__ float scl[3], scr[3];
    int tid = threadIdx.x;
    if (tid < 64) {
        float a = al1[tid], r = ar1[tid];
#pragma unroll
        for (int k = 0; k < 3; ++k) {
            float wv = W1[k*128 + tid];
            float vl = wv * a, vr = wv * r;
            for (int off = 32; off > 0; off >>= 1) {
                vl += __shfl_down(vl, off);
                vr += __shfl_down(vr, off);
            }
            if (tid == 0) { scl[k] = vl; scr[k] = vr; }
        }
    }
    __syncthreads();
    int n = blockIdx.x * 256 + tid;
    if (n < NN) {
        float f0 = feat[n*3], f1 = feat[n*3+1], f2 = feat[n*3+2];
        pfeat[n] = make_float4(f0, f1, f2, f0*scl[0] + f1*scl[1] + f2*scl[2]);
        er1[n] = f0*scr[0] + f1*scr[1] + f2*scr[2];
        float4 z = make_float4(0.f, 0.f, 0.f, 0.f);
        a0[n] = z; a1[n] = z; a2[n] = z; a3[n] = z;
    }
}

// layer-1 edge pass: gather pfeat[src] + er1[dst], p=exp(leaky), 4 fire-and-forget
// f32 atomics into SoA stride-4 accumulators (4 arrays -> 4 L2 channels in parallel)
__global__ void kE1_edge(const int* __restrict__ src, const int* __restrict__ dst,
                         const float4* __restrict__ pfeat, const float* __restrict__ er1,
                         float* __restrict__ a0, float* __restrict__ a1,
                         float* __restrict__ a2, float* __restrict__ a3) {
    int t = blockIdx.x * 256 + threadIdx.x;
    int e = t * 4;
    if (e + 4 > NE) return;
    int4 s4 = *(const int4*)(src + e);
    int4 d4 = *(const int4*)(dst + e);
    float4 vA = pfeat[s4.x], vB = pfeat[s4.y], vC = pfeat[s4.z], vD = pfeat[s4.w];
    float eA = er1[d4.x], eB = er1[d4.y], eC = er1[d4.z], eD = er1[d4.w];
    float u;
    u = vA.w + eA; u = (u >= 0.f) ? u : 0.2f * u; float pA = __expf(u);
    u = vB.w + eB; u = (u >= 0.f) ? u : 0.2f * u; float pB = __expf(u);
    u = vC.w + eC; u = (u >= 0.f) ? u : 0.2f * u; float pC = __expf(u);
    u = vD.w + eD; u = (u >= 0.f) ? u : 0.2f * u; float pD = __expf(u);
    atomicAdd(a0 + (size_t)d4.x*4, pA*vA.x); atomicAdd(a1 + (size_t)d4.x*4, pA*vA.y);
    atomicAdd(a2 + (size_t)d4.x*4, pA*vA.z); atomicAdd(a3 + (size_t)d4.x*4, pA);
    atomicAdd(a0 + (size_t)d4.y*4, pB*vB.x); atomicAdd(a1 + (size_t)d4.y*4, pB*vB.y);
    atomicAdd(a2 + (size_t)d4.y*4, pB*vB.z); atomicAdd(a3 + (size_t)d4.y*4, pB);
    atomicAdd(a0 + (size_t)d4.z*4, pC*vC.x); atomicAdd(a1 + (size_t)d4.z*4, pC*vC.y);
    atomicAdd(a2 + (size_t)d4.z*4, pC*vC.z); atomicAdd(a3 + (size_t)d4.z*4, pC);
    atomicAdd(a0 + (size_t)d4.w*4, pD*vD.x); atomicAdd(a1 + (size_t)d4.w*4, pD*vD.y);
    atomicAdd(a2 + (size_t)d4.w*4, pD*vD.z); atomicAdd(a3 + (size_t)d4.w*4, pD);
}

// per node: read 4 accumulated sums (coalesced), normalize, MLP -> z2 row (fp16),
// el2 in row slot [30], er2; zero den2 cursor for kE2a
__global__ void k4_node(const float* __restrict__ a0, const float* __restrict__ a1,
                        const float* __restrict__ a2, const float* __restrict__ a3,
                        const float* __restrict__ W1, const float* __restrict__ b1,
                        const float* __restrict__ W2, const float* __restrict__ al2,
                        const float* __restrict__ ar2,
                        __half* __restrict__ z2h, float* __restrict__ er2,
                        float* __restrict__ den2) {
    __shared__ float sW1[192], sb1[64], sW2[1920], sal2[30], sar2[30];
    int tid = threadIdx.x;
    for (int i = tid; i < 192; i += 256) sW1[i] = W1[(i >> 6)*128 + (i & 63)];
    for (int i = tid; i < 1920; i += 256) sW2[i] = W2[(i / 30)*60 + (i % 30)];
    if (tid < 64) sb1[tid] = b1[tid];
    if (tid < 30) { sal2[tid] = al2[tid]; sar2[tid] = ar2[tid]; }
    __syncthreads();
    int n = blockIdx.x * 256 + tid;
    if (n >= NN) return;
    float s0 = a0[(size_t)n*4], s1 = a1[(size_t)n*4], s2 = a2[(size_t)n*4], sp = a3[(size_t)n*4];
    float inv = (sp > 0.f) ? 1.f / sp : 0.f;
    float ax = s0 * inv, ay = s1 * inv, az = s2 * inv;
    float z[30];
#pragma unroll
    for (int c = 0; c < 30; ++c) z[c] = 0.f;
    for (int j = 0; j < 64; ++j) {
        float rj = fmaxf(ax*sW1[j] + ay*sW1[64 + j] + az*sW1[128 + j] + sb1[j], 0.f);
#pragma unroll
        for (int c = 0; c < 30; ++c) z[c] += rj * sW2[j*30 + c];
    }
    float sl = 0.f, sr = 0.f;
#pragma unroll
    for (int c = 0; c < 30; ++c) { sl += z[c] * sal2[c]; sr += z[c] * sar2[c]; }
    float4* outp = (float4*)(z2h + (size_t)n * 32);
    outp[0] = make_float4(PK2(z[0],z[1]),  PK2(z[2],z[3]),  PK2(z[4],z[5]),  PK2(z[6],z[7]));
    outp[1] = make_float4(PK2(z[8],z[9]),  PK2(z[10],z[11]),PK2(z[12],z[13]),PK2(z[14],z[15]));
    outp[2] = make_float4(PK2(z[16],z[17]),PK2(z[18],z[19]),PK2(z[20],z[21]),PK2(z[22],z[23]));
    outp[3] = make_float4(PK2(z[24],z[25]),PK2(z[26],z[27]),PK2(z[28],z[29]),PK2(sl, 0.f));
    er2[n] = sr;
    den2[(size_t)n*4] = 0.f;
}

// layer-2 denominator pass: gather el2 (2B from z2h row) + er2[dst], 1 fire-and-forget
// f32 atomic per edge into stride-4 den2
__global__ void kE2a_den(const int* __restrict__ src, const int* __restrict__ dst,
                         const __half* __restrict__ z2h, const float* __restrict__ er2,
                         float* __restrict__ den2) {
    int t = blockIdx.x * 256 + threadIdx.x;
    int e = t * 4;
    if (e + 4 > NE) return;
    int4 s4 = *(const int4*)(src + e);
    int4 d4 = *(const int4*)(dst + e);
    float lA = __half2float(z2h[(size_t)s4.x*32 + 30]);
    float lB = __half2float(z2h[(size_t)s4.y*32 + 30]);
    float lC = __half2float(z2h[(size_t)s4.z*32 + 30]);
    float lD = __half2float(z2h[(size_t)s4.w*32 + 30]);
    float eA = er2[d4.x], eB = er2[d4.y], eC = er2[d4.z], eD = er2[d4.w];
    float u;
    u = lA + eA; u = (u >= 0.f) ? u : 0.2f * u; atomicAdd(den2 + (size_t)d4.x*4, __expf(u));
    u = lB + eB; u = (u >= 0.f) ? u : 0.2f * u; atomicAdd(den2 + (size_t)d4.y*4, __expf(u));
    u = lC + eC; u = (u >= 0.f) ? u : 0.2f * u; atomicAdd(den2 + (size_t)d4.z*4, __expf(u));
    u = lD + eD; u = (u >= 0.f) ? u : 0.2f * u; atomicAdd(den2 + (size_t)d4.w*4, __expf(u));
}

// layer-2 colsum pass: per edge gather z2h[src] row (64B) + er2/den2[dst],
// w = p/den, accumulate w*z into 30 registers; block-reduce -> partials.
// Perfectly load-balanced (no per-node degree loop), no scatter.
__global__ void kE2b_col(const int* __restrict__ src, const int* __restrict__ dst,
                         const __half* __restrict__ z2h, const float* __restrict__ er2,
                         const float* __restrict__ den2, float* __restrict__ part) {
    int tid = threadIdx.x;
    int lane = tid & 63, wv = tid >> 6;
    float acc[30];
#pragma unroll
    for (int q = 0; q < 30; ++q) acc[q] = 0.f;
    int t = blockIdx.x * 256 + tid;
    int e = t * 4;
    if (e + 4 <= NE) {
        int4 s4 = *(const int4*)(src + e);
        int4 d4 = *(const int4*)(dst + e);
#define PROCW(r0, r1, r2, r3, er, dn) { \
            float el = __half2float(__low2half(__builtin_bit_cast(__half2, (r3).w))); \
            float ee = el + (er); \
            ee = (ee >= 0.f) ? ee : 0.2f * ee; \
            float wgt = __expf(ee) / (dn); \
            float2 f; \
            f = __half22float2(__builtin_bit_cast(__half2, (r0).x)); acc[0]  += wgt*f.x; acc[1]  += wgt*f.y; \
            f = __half22float2(__builtin_bit_cast(__half2, (r0).y)); acc[2]  += wgt*f.x; acc[3]  += wgt*f.y; \
            f = __half22float2(__builtin_bit_cast(__half2, (r0).z)); acc[4]  += wgt*f.x; acc[5]  += wgt*f.y; \
            f = __half22float2(__builtin_bit_cast(__half2, (r0).w)); acc[6]  += wgt*f.x; acc[7]  += wgt*f.y; \
            f = __half22float2(__builtin_bit_cast(__half2, (r1).x)); acc[8]  += wgt*f.x; acc[9]  += wgt*f.y; \
            f = __half22float2(__builtin_bit_cast(__half2, (r1).y)); acc[10] += wgt*f.x; acc[11] += wgt*f.y; \
            f = __half22float2(__builtin_bit_cast(__half2, (r1).z)); acc[12] += wgt*f.x; acc[13] += wgt*f.y; \
            f = __half22float2(__builtin_bit_cast(__half2, (r1).w)); acc[14] += wgt*f.x; acc[15] += wgt*f.y; \
            f = __half22float2(__builtin_bit_cast(__half2, (r2).x)); acc[16] += wgt*f.x; acc[17] += wgt*f.y; \
            f = __half22float2(__builtin_bit_cast(__half2, (r2).y)); acc[18] += wgt*f.x; acc[19] += wgt*f.y; \
            f = __half22float2(__builtin_bit_cast(__half2, (r2).z)); acc[20] += wgt*f.x; acc[21] += wgt*f.y; \
            f = __half22float2(__builtin_bit_cast(__half2, (r2).w)); acc[22] += wgt*f.x; acc[23] += wgt*f.y; \
            f = __half22float2(__builtin_bit_cast(__half2, (r3).x)); acc[24] += wgt*f.x; acc[25] += wgt*f.y; \
            f = __half22float2(__builtin_bit_cast(__half2, (r3).y)); acc[26] += wgt*f.x; acc[27] += wgt*f.y; \
            f = __half22float2(__builtin_bit_cast(__half2, (r3).z)); acc[28] += wgt*f.x; acc[29] += wgt*f.y; }
        {   // edges 0,1 in flight
            const float4* zA = (const float4*)(z2h + (size_t)s4.x * 32);
            const float4* zB = (const float4*)(z2h + (size_t)s4.y * 32);
            float4 a0_ = zA[0], a1_ = zA[1], a2_ = zA[2], a3_ = zA[3];
            float4 b0_ = zB[0], b1_ = zB[1], b2_ = zB[2], b3_ = zB[3];
            float erA = er2[d4.x], dnA = den2[(size_t)d4.x*4];
            float erB = er2[d4.y], dnB = den2[(size_t)d4.y*4];
            PROCW(a0_, a1_, a2_, a3_, erA, dnA)
            PROCW(b0_, b1_, b2_, b3_, erB, dnB)
        }
        {   // edges 2,3 in flight
            const float4* zA = (const float4*)(z2h + (size_t)s4.z * 32);
            const float4* zB = (const float4*)(z2h + (size_t)s4.w * 32);
            float4 a0_ = zA[0], a1_ = zA[1], a2_ = zA[2], a3_ = zA[3];
            float4 b0_ = zB[0], b1_ = zB[1], b2_ = zB[2], b3_ = zB[3];
            float erA = er2[d4.z], dnA = den2[(size_t)d4.z*4];
            float erB = er2[d4.w], dnB = den2[(size_t)d4.w*4];
            PROCW(a0_, a1_, a2_, a3_, erA, dnA)
            PROCW(b0_, b1_, b2_, b3_, erB, dnB)
        }
#undef PROCW
    }
#pragma unroll
    for (int q = 0; q < 30; ++q)
        for (int off = 32; off > 0; off >>= 1) acc[q] += __shfl_down(acc[q], off);
    __shared__ float sh[4][32];
    if (lane == 0) {
#pragma unroll
        for (int q = 0; q < 30; ++q) sh[wv][q] = acc[q];
    }
    __syncthreads();
    if (tid < 30)
        part[blockIdx.x * 32 + tid] = sh[0][tid] + sh[1][tid] + sh[2][tid] + sh[3][tid];
}

// single block: image path, parallel partial-sum over NB2 blocks, a00 = colsum/N + b2,
// concat, log_softmax
__global__ void k6_final(const float* __restrict__ x, const float* __restrict__ vocab,
                         const float* __restrict__ W_lin1, const float* __restrict__ w2,
                         const float* __restrict__ w3, const float* __restrict__ W4,
                         const float* __restrict__ b2, const float* __restrict__ part,
                         float* __restrict__ out) {
    __shared__ float sh[256];
    __shared__ float hvec[70];
    int tid = threadIdx.x;
    int r = tid >> 3, sub = tid & 7;
    float pt = 0.f;
    if (r < 30) {
        for (int k = sub; k < 512; k += 8) pt += W_lin1[r*512 + k] * x[k];
    }
    sh[tid] = pt;
    __syncthreads();
    if (tid < 30) {
        float hi = 0.f;
        for (int i = 0; i < 8; ++i) hi += sh[tid*8 + i];
        float acc = 0.f;
        for (int k = 0; k < 64; ++k) acc += w3[k] / (1.f + __expf(-w2[k] * hi));
        hvec[30 + tid] = 1.f / (1.f + __expf(-acc));
    }
    if (tid >= 64 && tid < 74) hvec[60 + (tid - 64)] = vocab[tid - 64];
    __syncthreads();             // all reads of sh done before reuse
    {
        int col = tid & 31, seg = tid >> 5;
        float s = 0.f;
        for (int b = seg; b < NB2; b += 8) s += part[b*32 + col];
        sh[tid] = s;
    }
    __syncthreads();
    if (tid < 30) {
        float cs = 0.f;
#pragma unroll
        for (int k = 0; k < 8; ++k) cs += sh[k*32 + tid];
        hvec[tid] = cs * (1.0f / (float)NN) + b2[tid];
    }
    __syncthreads();
    if (tid == 0) {
        float p0 = 0.f, p1 = 0.f;
        for (int k = 0; k < 70; ++k) {
            p0 += W4[k] * hvec[k];
            p1 += W4[70 + k] * hvec[k];
        }
        float mx = fmaxf(p0, p1);
        float l = logf(__expf(p0 - mx) + __expf(p1 - mx));
        out[0] = p0 - mx - l;
        out[1] = p1 - mx - l;
    }
}

extern "C" void kernel_launch(void* const* d_in, const int* in_sizes, int n_in,
                              void* d_out, int out_size, void* d_ws, size_t ws_size,
                              hipStream_t stream) {
    const float* x      = (const float*)d_in[0];
    const float* feat   = (const float*)d_in[1];
    const float* vocab  = (const float*)d_in[2];
    const int*   src    = (const int*)d_in[3];
    const int*   dst    = (const int*)d_in[4];
    const float* W_lin1 = (const float*)d_in[5];
    const float* w_c2   = (const float*)d_in[6];
    const float* w_c3   = (const float*)d_in[7];
    const float* W_lin4 = (const float*)d_in[8];
    const float* W1     = (const float*)d_in[9];
    const float* al1    = (const float*)d_in[10];
    const float* ar1    = (const float*)d_in[11];
    const float* b1     = (const float*)d_in[12];
    const float* W2     = (const float*)d_in[13];
    const float* al2    = (const float*)d_in[14];
    const float* ar2    = (const float*)d_in[15];
    const float* b2     = (const float*)d_in[16];
    float* out = (float*)d_out;
    float* w = (float*)d_ws;

    float4* pfeat = (float4*)(w + OFF_PFEAT);
    float*  er1   = w + OFF_ER1;
    float*  a0    = w + OFF_A0;
    float*  a1    = w + OFF_A1;
    float*  a2    = w + OFF_A2;
    float*  a3    = w + OFF_A3;
    float*  er2   = w + OFF_ER2;
    float*  den2  = w + OFF_DEN2;
    __half* z2h   = (__half*)(w + OFF_Z2H);
    float*  part  = w + OFF_PARTS;

    k0_prep<<<NPART, 256, 0, stream>>>(feat, W1, al1, ar1, pfeat, er1,
                                       (float4*)a0, (float4*)a1, (float4*)a2, (float4*)a3);
    kE1_edge<<<NB2, 256, 0, stream>>>(src, dst, pfeat, er1, a0, a1, a2, a3);
    k4_node<<<NPART, 256, 0, stream>>>(a0, a1, a2, a3, W1, b1, W2, al2, ar2, z2h, er2, den2);
    kE2a_den<<<NB2, 256, 0, stream>>>(src, dst, z2h, er2, den2);
    kE2b_col<<<NB2, 256, 0, stream>>>(src, dst, z2h, er2, den2, part);
    k6_final<<<1, 256, 0, stream>>>(x, vocab, W_lin1, w_c2, w_c3, W_lin4, b2, part, out);
}

// Round 5
// 194.009 us; speedup vs baseline: 2.2641x; 2.2641x over previous
//
#include <hip/hip_runtime.h>
#include <hip/hip_bf16.h>
#include <hip/hip_fp16.h>

#define NN 100000      // nodes
#define NE 1000000     // edges
#define NPART 391      // ceil(NN/256)  node-parallel grid
#define EPB 1024       // edges per block in edge passes
#define NBLK 977       // ceil(NE/EPB)
#define NBKT 391       // buckets: bucket = dst>>8 (256 nodes each), max idx 390
#define HSTRIDE 1024   // HT row stride (>= NBLK)

// ---------------- workspace layout (4-byte units) ----------------
#define OFF_CLCR     0              // f32[8]
#define OFF_PFEAT    16             // float4[NN] {f0,f1,f2,el1}  (byte 64, 16B aligned)
#define OFF_ER1      400016         // f32[NN]
#define OFF_ER2      500016         // f32[NN]
#define OFF_TOT      600016         // u32[NBKT]    bucket edge totals
#define OFF_BBASE    600407         // u32[NBKT+1]  bucket edge bases (exclusive scan)
#define OFF_HT       600800         // u32[NBKT*HSTRIDE]  per-(bucket,block) histo->prefix
#define OFF_PCK      1001184        // u32[NE]  bucket-partitioned packed edges
#define OFF_OFFS     2001184        // u32[NN+1]  final CSR offsets
#define OFF_BSRC     3001185        // u32[NE]  CSR payload (src)
#define OFF_Z2H      4001188        // half[32*NN] (64B rows; [30]=el2) byte 16B-aligned
#define OFF_PARTS    5601188        // f32[NPART*32]

#define PK2(a,b) __builtin_bit_cast(float, __floats2half2_rn((a),(b)))

// single tiny block: cl[k]=W1[k,:64]@al1, cr[k]=W1[k,:64]@ar1
__global__ void k0_clcr(const float* __restrict__ W1, const float* __restrict__ al1,
                        const float* __restrict__ ar1, float* __restrict__ clcr) {
    int j = threadIdx.x;
    float a = al1[j], r = ar1[j];
#pragma unroll
    for (int k = 0; k < 3; ++k) {
        float wv = W1[k*128 + j];
        float vl = wv * a, vr = wv * r;
        for (int off = 32; off > 0; off >>= 1) {
            vl += __shfl_down(vl, off);
            vr += __shfl_down(vr, off);
        }
        if (j == 0) { clcr[k] = vl; clcr[4 + k] = vr; }
    }
}

// pass A: per-block LDS histogram over 391 buckets (no global atomics);
// also packs pfeat/er1 (grid covers all nodes)
__global__ void kA_hist(const int* __restrict__ dst, const float* __restrict__ feat,
                        const float* __restrict__ clcr, unsigned* __restrict__ HT,
                        float4* __restrict__ pfeat, float* __restrict__ er1) {
    __shared__ unsigned h[NBKT];
    int tid = threadIdx.x;
    for (int i = tid; i < NBKT; i += 256) h[i] = 0u;
    __syncthreads();
    int e0 = blockIdx.x * EPB + tid * 4;
    if (e0 + 4 <= NE) {
        int4 d4 = *(const int4*)(dst + e0);
        atomicAdd(&h[d4.x >> 8], 1u);
        atomicAdd(&h[d4.y >> 8], 1u);
        atomicAdd(&h[d4.z >> 8], 1u);
        atomicAdd(&h[d4.w >> 8], 1u);
    } else {
        for (int e = e0; e < NE; ++e) atomicAdd(&h[dst[e] >> 8], 1u);
    }
    int n = blockIdx.x * 256 + tid;
    if (n < NN) {
        float c0 = clcr[0], c1 = clcr[1], c2 = clcr[2];
        float c4 = clcr[4], c5 = clcr[5], c6 = clcr[6];
        float f0 = feat[n*3], f1 = feat[n*3+1], f2 = feat[n*3+2];
        pfeat[n] = make_float4(f0, f1, f2, f0*c0 + f1*c1 + f2*c2);
        er1[n] = f0*c4 + f1*c5 + f2*c6;
    }
    __syncthreads();
    for (int k = tid; k < NBKT; k += 256) HT[(size_t)k * HSTRIDE + blockIdx.x] = h[k];
}

// pass B: one block per bucket: exclusive scan of HT[k][0..NBLK) in place + total
__global__ void kB_scan(unsigned* __restrict__ HT, unsigned* __restrict__ tot) {
    __shared__ unsigned sh[256];
    int t = threadIdx.x;
    size_t row = (size_t)blockIdx.x * HSTRIDE;
    unsigned v[4], ex[4];
    unsigned s = 0;
#pragma unroll
    for (int j = 0; j < 4; ++j) {
        int b = t*4 + j;
        v[j] = (b < NBLK) ? HT[row + b] : 0u;
        ex[j] = s;
        s += v[j];
    }
    sh[t] = s;
    __syncthreads();
    for (int off = 1; off < 256; off <<= 1) {
        unsigned u = (t >= off) ? sh[t - off] : 0u;
        __syncthreads();
        sh[t] += u;
        __syncthreads();
    }
    unsigned base = sh[t] - s;   // exclusive across threads
#pragma unroll
    for (int j = 0; j < 4; ++j) {
        int b = t*4 + j;
        if (b < NBLK) HT[row + b] = base + ex[j];
    }
    if (t == 255) tot[blockIdx.x] = sh[255];
}

// pass B2: single block: exclusive scan of bucket totals -> bucket bases
__global__ void kB2_base(const unsigned* __restrict__ tot, unsigned* __restrict__ bbase) {
    __shared__ unsigned sh[512];
    int t = threadIdx.x;
    unsigned v = (t < NBKT) ? tot[t] : 0u;
    sh[t] = v;
    __syncthreads();
    for (int off = 1; off < 512; off <<= 1) {
        unsigned u = (t >= off) ? sh[t - off] : 0u;
        __syncthreads();
        sh[t] += u;
        __syncthreads();
    }
    if (t < NBKT) bbase[t] = sh[t] - v;
    if (t == NBKT - 1) bbase[NBKT] = sh[t];   // = NE
}

// pass C: re-read edges; rank within (block,bucket) via LDS returning atomics;
// scatter packed u32 {src | (dst&255)<<17} into the bucket-partitioned array
__global__ void kC_scatter(const int* __restrict__ src, const int* __restrict__ dst,
                           const unsigned* __restrict__ HT, const unsigned* __restrict__ bbase,
                           unsigned* __restrict__ pck) {
    __shared__ unsigned sBase[NBKT];
    __shared__ unsigned sCnt[NBKT];
    int tid = threadIdx.x;
    for (int k = tid; k < NBKT; k += 256) {
        sBase[k] = bbase[k] + HT[(size_t)k * HSTRIDE + blockIdx.x];
        sCnt[k] = 0u;
    }
    __syncthreads();
    int e0 = blockIdx.x * EPB + tid * 4;
    if (e0 + 4 <= NE) {
        int4 s4 = *(const int4*)(src + e0);
        int4 d4 = *(const int4*)(dst + e0);
        unsigned k, r;
        k = (unsigned)d4.x >> 8; r = atomicAdd(&sCnt[k], 1u);
        pck[sBase[k] + r] = (unsigned)s4.x | (((unsigned)d4.x & 255u) << 17);
        k = (unsigned)d4.y >> 8; r = atomicAdd(&sCnt[k], 1u);
        pck[sBase[k] + r] = (unsigned)s4.y | (((unsigned)d4.y & 255u) << 17);
        k = (unsigned)d4.z >> 8; r = atomicAdd(&sCnt[k], 1u);
        pck[sBase[k] + r] = (unsigned)s4.z | (((unsigned)d4.z & 255u) << 17);
        k = (unsigned)d4.w >> 8; r = atomicAdd(&sCnt[k], 1u);
        pck[sBase[k] + r] = (unsigned)s4.w | (((unsigned)d4.w & 255u) << 17);
    } else {
        for (int e = e0; e < NE; ++e) {
            unsigned d = (unsigned)dst[e];
            unsigned k = d >> 8;
            unsigned r = atomicAdd(&sCnt[k], 1u);
            pck[sBase[k] + r] = (unsigned)src[e] | ((d & 255u) << 17);
        }
    }
}

// pass D: one block per bucket: LDS histogram over 256 nodes, scan -> offsets[];
// second (L2-hot) pass scatters src into final CSR bsrc within the bucket region
__global__ void kD_local(const unsigned* __restrict__ bbase, const unsigned* __restrict__ pck,
                         unsigned* __restrict__ offsets, unsigned* __restrict__ bsrc) {
    __shared__ unsigned h[256];
    __shared__ unsigned pr[256];
    __shared__ unsigned cur[256];
    int tid = threadIdx.x;
    unsigned bb = bbase[blockIdx.x], be = bbase[blockIdx.x + 1];
    h[tid] = 0u; cur[tid] = 0u;
    __syncthreads();
    for (unsigned i = bb + tid; i < be; i += 256) atomicAdd(&h[pck[i] >> 17], 1u);
    __syncthreads();
    unsigned v = h[tid];
    pr[tid] = v;
    __syncthreads();
    for (int off = 1; off < 256; off <<= 1) {
        unsigned u = (tid >= off) ? pr[tid - off] : 0u;
        __syncthreads();
        pr[tid] += u;
        __syncthreads();
    }
    pr[tid] -= v;                 // exclusive prefix within bucket
    int node = blockIdx.x * 256 + tid;
    if (node <= NN) offsets[node] = bb + pr[tid];   // node==NN: writes offsets[NN]=NE
    __syncthreads();
    for (unsigned i = bb + tid; i < be; i += 256) {
        unsigned w = pck[i];
        unsigned j = w >> 17;
        unsigned r = atomicAdd(&cur[j], 1u);
        bsrc[bb + pr[j] + r] = w & 0x1FFFFu;
    }
}

// per node: gather pfeat[src] (4-deep MLP unroll), recompute p, aggregate; then z2 row
// via 30 register accumulators, fp16 pack, er2
__global__ void k4_node(const unsigned* __restrict__ offsets, const unsigned* __restrict__ bsrc,
                        const float4* __restrict__ pfeat, const float* __restrict__ er1,
                        const float* __restrict__ W1, const float* __restrict__ b1,
                        const float* __restrict__ W2, const float* __restrict__ al2,
                        const float* __restrict__ ar2,
                        __half* __restrict__ z2h, float* __restrict__ er2) {
    __shared__ float sW1[192], sb1[64], sW2[1920], sal2[30], sar2[30];
    int tid = threadIdx.x;
    for (int i = tid; i < 192; i += 256) sW1[i] = W1[(i >> 6)*128 + (i & 63)];
    for (int i = tid; i < 1920; i += 256) sW2[i] = W2[(i / 30)*60 + (i % 30)];
    if (tid < 64) sb1[tid] = b1[tid];
    if (tid < 30) { sal2[tid] = al2[tid]; sar2[tid] = ar2[tid]; }
    __syncthreads();
    int n = blockIdx.x * 256 + tid;
    if (n >= NN) return;
    unsigned beg = offsets[n], end = offsets[n + 1];
    float erd = er1[n];
    float s0 = 0.f, s1 = 0.f, s2 = 0.f, sp = 0.f;
    unsigned i = beg;
    for (; i + 4 <= end; i += 4) {           // 4 independent gathers in flight
        unsigned sA = bsrc[i], sB = bsrc[i+1], sC = bsrc[i+2], sD = bsrc[i+3];
        float4 vA = pfeat[sA], vB = pfeat[sB], vC = pfeat[sC], vD = pfeat[sD];
        float eA = vA.w + erd; eA = (eA >= 0.f) ? eA : 0.2f * eA; float pA = __expf(eA);
        s0 += pA * vA.x; s1 += pA * vA.y; s2 += pA * vA.z; sp += pA;
        float eB = vB.w + erd; eB = (eB >= 0.f) ? eB : 0.2f * eB; float pB = __expf(eB);
        s0 += pB * vB.x; s1 += pB * vB.y; s2 += pB * vB.z; sp += pB;
        float eC = vC.w + erd; eC = (eC >= 0.f) ? eC : 0.2f * eC; float pC = __expf(eC);
        s0 += pC * vC.x; s1 += pC * vC.y; s2 += pC * vC.z; sp += pC;
        float eD = vD.w + erd; eD = (eD >= 0.f) ? eD : 0.2f * eD; float pD = __expf(eD);
        s0 += pD * vD.x; s1 += pD * vD.y; s2 += pD * vD.z; sp += pD;
    }
    for (; i < end; ++i) {
        unsigned s = bsrc[i];
        float4 v = pfeat[s];
        float ee = v.w + erd;
        ee = (ee >= 0.f) ? ee : 0.2f * ee;
        float p = __expf(ee);
        s0 += p * v.x; s1 += p * v.y; s2 += p * v.z; sp += p;
    }
    float inv = (sp > 0.f) ? 1.f / sp : 0.f;
    float ax = s0 * inv, ay = s1 * inv, az = s2 * inv;
    float z[30];
#pragma unroll
    for (int c = 0; c < 30; ++c) z[c] = 0.f;
    for (int j = 0; j < 64; ++j) {
        float rj = fmaxf(ax*sW1[j] + ay*sW1[64 + j] + az*sW1[128 + j] + sb1[j], 0.f);
#pragma unroll
        for (int c = 0; c < 30; ++c) z[c] += rj * sW2[j*30 + c];
    }
    float sl = 0.f, sr = 0.f;
#pragma unroll
    for (int c = 0; c < 30; ++c) { sl += z[c] * sal2[c]; sr += z[c] * sar2[c]; }
    float4* outp = (float4*)(z2h + (size_t)n * 32);
    outp[0] = make_float4(PK2(z[0],z[1]),  PK2(z[2],z[3]),  PK2(z[4],z[5]),  PK2(z[6],z[7]));
    outp[1] = make_float4(PK2(z[8],z[9]),  PK2(z[10],z[11]),PK2(z[12],z[13]),PK2(z[14],z[15]));
    outp[2] = make_float4(PK2(z[16],z[17]),PK2(z[18],z[19]),PK2(z[20],z[21]),PK2(z[22],z[23]));
    outp[3] = make_float4(PK2(z[24],z[25]),PK2(z[26],z[27]),PK2(z[28],z[29]),PK2(sl, 0.f));
    er2[n] = sr;
}

// per node: gather fp16 z2 rows (64 B, el2 included; 2 rows in flight),
// softmax-weighted colsum partials
__global__ void k5_layer2(const unsigned* __restrict__ offsets, const unsigned* __restrict__ bsrc,
                          const __half* __restrict__ z2h, const float* __restrict__ er2,
                          float* __restrict__ part) {
    int tid = threadIdx.x;
    int lane = tid & 63, wv = tid >> 6;
    int n = blockIdx.x * 256 + tid;
    float acc[32];
#pragma unroll
    for (int q = 0; q < 32; ++q) acc[q] = 0.f;
    if (n < NN) {
        unsigned beg = offsets[n], end = offsets[n + 1];
        float erd = er2[n];
        float sp = 0.f;
#define PROC(r0, r1, r2, r3) { \
            float el = __half2float(__low2half(__builtin_bit_cast(__half2, (r3).w))); \
            float ee = el + erd; \
            ee = (ee >= 0.f) ? ee : 0.2f * ee; \
            float p = __expf(ee); \
            sp += p; \
            float2 f; \
            f = __half22float2(__builtin_bit_cast(__half2, (r0).x)); acc[0]  += p*f.x; acc[1]  += p*f.y; \
            f = __half22float2(__builtin_bit_cast(__half2, (r0).y)); acc[2]  += p*f.x; acc[3]  += p*f.y; \
            f = __half22float2(__builtin_bit_cast(__half2, (r0).z)); acc[4]  += p*f.x; acc[5]  += p*f.y; \
            f = __half22float2(__builtin_bit_cast(__half2, (r0).w)); acc[6]  += p*f.x; acc[7]  += p*f.y; \
            f = __half22float2(__builtin_bit_cast(__half2, (r1).x)); acc[8]  += p*f.x; acc[9]  += p*f.y; \
            f = __half22float2(__builtin_bit_cast(__half2, (r1).y)); acc[10] += p*f.x; acc[11] += p*f.y; \
            f = __half22float2(__builtin_bit_cast(__half2, (r1).z)); acc[12] += p*f.x; acc[13] += p*f.y; \
            f = __half22float2(__builtin_bit_cast(__half2, (r1).w)); acc[14] += p*f.x; acc[15] += p*f.y; \
            f = __half22float2(__builtin_bit_cast(__half2, (r2).x)); acc[16] += p*f.x; acc[17] += p*f.y; \
            f = __half22float2(__builtin_bit_cast(__half2, (r2).y)); acc[18] += p*f.x; acc[19] += p*f.y; \
            f = __half22float2(__builtin_bit_cast(__half2, (r2).z)); acc[20] += p*f.x; acc[21] += p*f.y; \
            f = __half22float2(__builtin_bit_cast(__half2, (r2).w)); acc[22] += p*f.x; acc[23] += p*f.y; \
            f = __half22float2(__builtin_bit_cast(__half2, (r3).x)); acc[24] += p*f.x; acc[25] += p*f.y; \
            f = __half22float2(__builtin_bit_cast(__half2, (r3).y)); acc[26] += p*f.x; acc[27] += p*f.y; \
            f = __half22float2(__builtin_bit_cast(__half2, (r3).z)); acc[28] += p*f.x; acc[29] += p*f.y; \
            f = __half22float2(__builtin_bit_cast(__half2, (r3).w)); acc[30] += p*f.x; acc[31] += p*f.y; }
        unsigned i = beg;
        for (; i + 2 <= end; i += 2) {       // 2 rows (8 float4 loads) in flight
            unsigned sA = bsrc[i], sB = bsrc[i+1];
            const float4* zA = (const float4*)(z2h + (size_t)sA * 32);
            const float4* zB = (const float4*)(z2h + (size_t)sB * 32);
            float4 a0 = zA[0], a1 = zA[1], a2 = zA[2], a3 = zA[3];
            float4 b0 = zB[0], b1 = zB[1], b2 = zB[2], b3 = zB[3];
            PROC(a0, a1, a2, a3)
            PROC(b0, b1, b2, b3)
        }
        for (; i < end; ++i) {
            unsigned s = bsrc[i];
            const float4* zr = (const float4*)(z2h + (size_t)s * 32);
            float4 r0 = zr[0], r1 = zr[1], r2 = zr[2], r3 = zr[3];
            PROC(r0, r1, r2, r3)
        }
#undef PROC
        float inv = (sp > 0.f) ? 1.f / sp : 0.f;
#pragma unroll
        for (int q = 0; q < 32; ++q) acc[q] *= inv;
    }
#pragma unroll
    for (int q = 0; q < 32; ++q)
        for (int off = 32; off > 0; off >>= 1) acc[q] += __shfl_down(acc[q], off);
    __shared__ float sh[4][32];
    if (lane == 0) {
#pragma unroll
        for (int q = 0; q < 32; ++q) sh[wv][q] = acc[q];
    }
    __syncthreads();
    if (tid < 32)
        part[blockIdx.x * 32 + tid] = sh[0][tid] + sh[1][tid] + sh[2][tid] + sh[3][tid];
}

// single block: image path, sum partials, a00 = colsum/N + b2[0], concat, log_softmax
__global__ void k6_final(const float* __restrict__ x, const float* __restrict__ vocab,
                         const float* __restrict__ W_lin1, const float* __restrict__ w2,
                         const float* __restrict__ w3, const float* __restrict__ W4,
                         const float* __restrict__ b2, const float* __restrict__ part,
                         float* __restrict__ out) {
    __shared__ float sh[256];
    __shared__ float hvec[70];
    int tid = threadIdx.x;
    int r = tid >> 3, sub = tid & 7;
    float pt = 0.f;
    if (r < 30) {
        for (int k = sub; k < 512; k += 8) pt += W_lin1[r*512 + k] * x[k];
    }
    sh[tid] = pt;
    __syncthreads();
    if (tid < 30) {
        float hi = 0.f;
        for (int i = 0; i < 8; ++i) hi += sh[tid*8 + i];
        float acc = 0.f;
        for (int k = 0; k < 64; ++k) acc += w3[k] / (1.f + __expf(-w2[k] * hi));
        hvec[30 + tid] = 1.f / (1.f + __expf(-acc));
        float cs = 0.f;
        for (int b = 0; b < NPART; ++b) cs += part[b*32 + tid];
        hvec[tid] = cs * (1.0f / (float)NN) + b2[tid];
    }
    if (tid >= 64 && tid < 74) hvec[60 + (tid - 64)] = vocab[tid - 64];
    __syncthreads();
    if (tid == 0) {
        float p0 = 0.f, p1 = 0.f;
        for (int k = 0; k < 70; ++k) {
            p0 += W4[k] * hvec[k];
            p1 += W4[70 + k] * hvec[k];
        }
        float mx = fmaxf(p0, p1);
        float l = logf(__expf(p0 - mx) + __expf(p1 - mx));
        out[0] = p0 - mx - l;
        out[1] = p1 - mx - l;
    }
}

extern "C" void kernel_launch(void* const* d_in, const int* in_sizes, int n_in,
                              void* d_out, int out_size, void* d_ws, size_t ws_size,
                              hipStream_t stream) {
    const float* x      = (const float*)d_in[0];
    const float* feat   = (const float*)d_in[1];
    const float* vocab  = (const float*)d_in[2];
    const int*   src    = (const int*)d_in[3];
    const int*   dst    = (const int*)d_in[4];
    const float* W_lin1 = (const float*)d_in[5];
    const float* w_c2   = (const float*)d_in[6];
    const float* w_c3   = (const float*)d_in[7];
    const float* W_lin4 = (const float*)d_in[8];
    const float* W1     = (const float*)d_in[9];
    const float* al1    = (const float*)d_in[10];
    const float* ar1    = (const float*)d_in[11];
    const float* b1     = (const float*)d_in[12];
    const float* W2     = (const float*)d_in[13];
    const float* al2    = (const float*)d_in[14];
    const float* ar2    = (const float*)d_in[15];
    const float* b2     = (const float*)d_in[16];
    float* out = (float*)d_out;
    float* w = (float*)d_ws;

    float*    clcr    = w + OFF_CLCR;
    float4*   pfeat   = (float4*)(w + OFF_PFEAT);
    float*    er1     = w + OFF_ER1;
    float*    er2     = w + OFF_ER2;
    unsigned* tot     = (unsigned*)(w + OFF_TOT);
    unsigned* bbase   = (unsigned*)(w + OFF_BBASE);
    unsigned* HT      = (unsigned*)(w + OFF_HT);
    unsigned* pck     = (unsigned*)(w + OFF_PCK);
    unsigned* offsets = (unsigned*)(w + OFF_OFFS);
    unsigned* bsrc    = (unsigned*)(w + OFF_BSRC);
    __half*   z2h     = (__half*)(w + OFF_Z2H);
    float*    part    = w + OFF_PARTS;

    k0_clcr<<<1, 64, 0, stream>>>(W1, al1, ar1, clcr);
    kA_hist<<<NBLK, 256, 0, stream>>>(dst, feat, clcr, HT, pfeat, er1);
    kB_scan<<<NBKT, 256, 0, stream>>>(HT, tot);
    kB2_base<<<1, 512, 0, stream>>>(tot, bbase);
    kC_scatter<<<NBLK, 256, 0, stream>>>(src, dst, HT, bbase, pck);
    kD_local<<<NBKT, 256, 0, stream>>>(bbase, pck, offsets, bsrc);
    k4_node<<<NPART, 256, 0, stream>>>(offsets, bsrc, pfeat, er1, W1, b1, W2, al2, ar2, z2h, er2);
    k5_layer2<<<NPART, 256, 0, stream>>>(offsets, bsrc, z2h, er2, part);
    k6_final<<<1, 256, 0, stream>>>(x, vocab, W_lin1, w_c2, w_c3, W_lin4, b2, part, out);
}